// Round 12
// baseline (95.766 us; speedup 1.0000x reference)
//
#include <hip/hip_runtime.h>
#include <hip/hip_bf16.h>

#define B_ROWS 8192
#define E_DIM  1024
#define MARGIN 0.2f
#define BK 32
#define NSTEPS (E_DIM / BK)   // 32

typedef __bf16 bf16x8 __attribute__((ext_vector_type(8)));
typedef float  f32x4  __attribute__((ext_vector_type(4)));

// blocks [0,4096): c = 0.4*m + 0.6*tr_m (bf16);
// blocks [4096,5120): Wt[n][e] = bf16(W[e][n]); blocks [5120,5152): zero delta.
__global__ __launch_bounds__(256)
void prep_combo(const float* __restrict__ m, const float* __restrict__ trm,
                __bf16* __restrict__ c,
                const float* __restrict__ W, __bf16* __restrict__ Wt,
                float* __restrict__ delta) {
    if (blockIdx.x < 4096) {
        size_t i = ((size_t)blockIdx.x * blockDim.x + threadIdx.x) * 8;
        float4 m0 = *(const float4*)(m + i);
        float4 m1 = *(const float4*)(m + i + 4);
        float4 t0 = *(const float4*)(trm + i);
        float4 t1 = *(const float4*)(trm + i + 4);
        bf16x8 v;
        v[0] = (__bf16)(0.4f*m0.x + 0.6f*t0.x);
        v[1] = (__bf16)(0.4f*m0.y + 0.6f*t0.y);
        v[2] = (__bf16)(0.4f*m0.z + 0.6f*t0.z);
        v[3] = (__bf16)(0.4f*m0.w + 0.6f*t0.w);
        v[4] = (__bf16)(0.4f*m1.x + 0.6f*t1.x);
        v[5] = (__bf16)(0.4f*m1.y + 0.6f*t1.y);
        v[6] = (__bf16)(0.4f*m1.z + 0.6f*t1.z);
        v[7] = (__bf16)(0.4f*m1.w + 0.6f*t1.w);
        *(bf16x8*)(c + i) = v;
    } else if (blockIdx.x < 5120) {
        __shared__ float tile[32][33];
        const int tb = blockIdx.x - 4096;
        const int bx = (tb & 31) * 32;          // n base
        const int by = (tb >> 5) * 32;          // e base
        const int tx = threadIdx.x & 31;
        const int ty0 = threadIdx.x >> 5;       // 8 rows/thread
#pragma unroll
        for (int r = 0; r < 32; r += 8)
            tile[r + ty0][tx] = W[(size_t)(by + r + ty0) * E_DIM + bx + tx];
        __syncthreads();
#pragma unroll
        for (int r = 0; r < 32; r += 8)
            Wt[(size_t)(bx + r + ty0) * E_DIM + by + tx] = (__bf16)tile[tx][r + ty0];
    } else {
        delta[(blockIdx.x - 5120) * 256 + threadIdx.x] = 0.f;
    }
}

// No-LDS register GEMM: u = c @ Wt^T. Each wave owns a 64x64 output tile
// (4x4 MFMA frags); A/B fragments loaded DIRECTLY from global (16 B/lane,
// 64 B-line granularity, L1/L2-served: working set is L2/L3-resident).
// Register double-buffer, unrolled x2: loads(t+1) issued before mfmas(t),
// no barriers, no LDS, no bank conflicts. Fused epilogue: rowwise dot with
// (Ais - Aem), 16-lane reduce, atomicAdd into delta[].
__global__ __launch_bounds__(256)
void gemm_dot(const __bf16* __restrict__ Cm, const __bf16* __restrict__ Wt,
              const float* __restrict__ Ais, const float* __restrict__ Aem,
              float* __restrict__ delta) {
    const int tid  = threadIdx.x;
    const int lane = tid & 63;
    const int wave = tid >> 6;
    const int lr   = lane & 15;
    const int hi   = lane >> 4;
    const int wr   = wave >> 1, wc = wave & 1;

    // XCD swizzle: xcd owns 8 row-panels x 8 colb; per-XCD reuse set =
    // 8 c-panels (4 MiB) + Wt (2 MiB) ~ L2-resident, L3 backs the rest.
    const int bid = blockIdx.x;
    const int xcd = bid & 7;
    const int q   = bid >> 3;            // 0..63
    const int rb  = (xcd * 8 + (q >> 3)) * 128;
    const int cb  = (q & 7) * 128;

    // per-lane fragment bases (A-frag mi: rows rb+wr*64+mi*16+lr;
    // B-frag ni: rows cb+wc*64+ni*16+lr; k-slice at hi*8)
    const __bf16* pa = Cm + (size_t)(rb + wr * 64 + lr) * E_DIM + hi * 8;
    const __bf16* pb = Wt + (size_t)(cb + wc * 64 + lr) * E_DIM + hi * 8;

    bf16x8 a0[4], b0[4], a1[4], b1[4];
    f32x4 acc[4][4] = {};

    auto loads = [&](bf16x8* A, bf16x8* B, int k) {
#pragma unroll
        for (int i = 0; i < 4; ++i) {
            A[i] = *(const bf16x8*)(pa + (size_t)(i * 16) * E_DIM + k);
            B[i] = *(const bf16x8*)(pb + (size_t)(i * 16) * E_DIM + k);
        }
    };
    auto mfmas = [&](bf16x8* A, bf16x8* B) {
#pragma unroll
        for (int mi = 0; mi < 4; ++mi)
#pragma unroll
            for (int ni = 0; ni < 4; ++ni)
                acc[mi][ni] = __builtin_amdgcn_mfma_f32_16x16x32_bf16(
                    A[mi], B[ni], acc[mi][ni], 0, 0, 0);
    };

    loads(a0, b0, 0);
#pragma unroll
    for (int t = 0; t < NSTEPS; t += 2) {
        loads(a1, b1, (t + 1) * BK);      // in flight across mfmas(a0,b0)
        mfmas(a0, b0);
        if (t + 2 < NSTEPS) loads(a0, b0, (t + 2) * BK);
        mfmas(a1, b1);
    }

    // epilogue: delta[r] += sum_col u[r][col] * (Ais - Aem)[r][col]
    // C/D layout (16x16x32): col = lane&15, row = (lane>>4)*4 + reg
    const int colbase = cb + wc * 64 + lr;
    const int rowbase = rb + wr * 64 + hi * 4;
#pragma unroll
    for (int mi = 0; mi < 4; ++mi) {
#pragma unroll
        for (int jj = 0; jj < 4; ++jj) {
            const int r = rowbase + mi * 16 + jj;
            float v = 0.f;
#pragma unroll
            for (int ni = 0; ni < 4; ++ni) {
                const size_t idx = (size_t)r * E_DIM + colbase + ni * 16;
                v += acc[mi][ni][jj] * (Ais[idx] - Aem[idx]);
            }
            v += __shfl_xor(v, 1);
            v += __shfl_xor(v, 2);
            v += __shfl_xor(v, 4);
            v += __shfl_xor(v, 8);
            if (lr == 0) atomicAdd(&delta[r], v);
        }
    }
}

__global__ void hinge_sum(const float* __restrict__ delta, float* __restrict__ out) {
    float s = 0.f;
    for (int i = threadIdx.x; i < B_ROWS; i += 256)
        s += fmaxf(MARGIN + delta[i], 0.f);
#pragma unroll
    for (int off = 32; off > 0; off >>= 1) s += __shfl_down(s, off);
    __shared__ float wsum[4];
    int lane = threadIdx.x & 63, w = threadIdx.x >> 6;
    if (lane == 0) wsum[w] = s;
    __syncthreads();
    if (threadIdx.x == 0) out[0] = wsum[0] + wsum[1] + wsum[2] + wsum[3];
}

extern "C" void kernel_launch(void* const* d_in, const int* in_sizes, int n_in,
                              void* d_out, int out_size, void* d_ws, size_t ws_size,
                              hipStream_t stream) {
    const float* A_is = (const float*)d_in[0];
    const float* A_em = (const float*)d_in[1];
    const float* m    = (const float*)d_in[2];
    const float* tr_m = (const float*)d_in[3];
    const float* W    = (const float*)d_in[4];
    // d_in[5] = b : cancels in diag_is - diag_em, unused.
    float* out = (float*)d_out;

    char* ws = (char*)d_ws;
    __bf16* c     = (__bf16*)ws;                              // 16 MiB
    __bf16* wt    = (__bf16*)(ws + (size_t)16 * 1024 * 1024); //  2 MiB
    float*  delta = (float*) (ws + (size_t)18 * 1024 * 1024); // 32 KiB

    prep_combo<<<5152, 256, 0, stream>>>(m, tr_m, c, W, wt, delta);
    gemm_dot<<<512, 256, 0, stream>>>(c, wt, A_is, A_em, delta);
    hinge_sum<<<1, 256, 0, stream>>>(delta, out);
}

// Round 13
// 94.140 us; speedup vs baseline: 1.0173x; 1.0173x over previous
//
#include <hip/hip_runtime.h>
#include <hip/hip_bf16.h>

#define B_ROWS 8192
#define E_DIM  1024
#define MARGIN 0.2f
#define BK 32
#define NSTEPS (E_DIM / BK)   // 32

typedef __bf16 bf16x8 __attribute__((ext_vector_type(8)));
typedef float  f32x4  __attribute__((ext_vector_type(4)));

// blocks [0,4096): c = 0.4*m + 0.6*tr_m (bf16);
// blocks [4096,5120): Wt[n][e] = bf16(W[e][n]); blocks [5120,5152): zero delta.
__global__ __launch_bounds__(256)
void prep_combo(const float* __restrict__ m, const float* __restrict__ trm,
                __bf16* __restrict__ c,
                const float* __restrict__ W, __bf16* __restrict__ Wt,
                float* __restrict__ delta) {
    if (blockIdx.x < 4096) {
        size_t i = ((size_t)blockIdx.x * blockDim.x + threadIdx.x) * 8;
        float4 m0 = *(const float4*)(m + i);
        float4 m1 = *(const float4*)(m + i + 4);
        float4 t0 = *(const float4*)(trm + i);
        float4 t1 = *(const float4*)(trm + i + 4);
        bf16x8 v;
        v[0] = (__bf16)(0.4f*m0.x + 0.6f*t0.x);
        v[1] = (__bf16)(0.4f*m0.y + 0.6f*t0.y);
        v[2] = (__bf16)(0.4f*m0.z + 0.6f*t0.z);
        v[3] = (__bf16)(0.4f*m0.w + 0.6f*t0.w);
        v[4] = (__bf16)(0.4f*m1.x + 0.6f*t1.x);
        v[5] = (__bf16)(0.4f*m1.y + 0.6f*t1.y);
        v[6] = (__bf16)(0.4f*m1.z + 0.6f*t1.z);
        v[7] = (__bf16)(0.4f*m1.w + 0.6f*t1.w);
        *(bf16x8*)(c + i) = v;
    } else if (blockIdx.x < 5120) {
        __shared__ float tile[32][33];
        const int tb = blockIdx.x - 4096;
        const int bx = (tb & 31) * 32;          // n base
        const int by = (tb >> 5) * 32;          // e base
        const int tx = threadIdx.x & 31;
        const int ty0 = threadIdx.x >> 5;       // 8 rows/thread
#pragma unroll
        for (int r = 0; r < 32; r += 8)
            tile[r + ty0][tx] = W[(size_t)(by + r + ty0) * E_DIM + bx + tx];
        __syncthreads();
#pragma unroll
        for (int r = 0; r < 32; r += 8)
            Wt[(size_t)(bx + r + ty0) * E_DIM + by + tx] = (__bf16)tile[tx][r + ty0];
    } else {
        delta[(blockIdx.x - 5120) * 256 + threadIdx.x] = 0.f;
    }
}

// Asm-pinned no-LDS register GEMM (AITER pattern): ring-of-3 REGISTER buffers,
// loads issued by inline-asm global_load_dwordx4 (hipcc cannot sink them),
// consumed under counted s_waitcnt vmcnt(16) (never 0 mid-loop). No LDS, no
// barriers, no bank conflicts; waves free-run. Per iter/wave: 8 asm loads
// (tile t+2) + 16 MFMA (tile t). Flight = 2 iters. Full unroll -> all ring
// indices static (rule #20); sched_barrier(0) after every waitcnt (rule #18).
#define LOAD16(dst, base, koff)                                          \
    asm volatile("global_load_dwordx4 %0, %1, off"                       \
                 : "=v"(dst) : "v"((base) + (unsigned long long)(koff)) : "memory")

#define VMW(N)  do { asm volatile("s_waitcnt vmcnt(" #N ")" ::: "memory"); \
                     __builtin_amdgcn_sched_barrier(0); } while (0)

__global__ __launch_bounds__(256)
void gemm_dot(const __bf16* __restrict__ Cm, const __bf16* __restrict__ Wt,
              const float* __restrict__ Ais, const float* __restrict__ Aem,
              float* __restrict__ delta) {
    const int tid  = threadIdx.x;
    const int lane = tid & 63;
    const int wave = tid >> 6;
    const int lr   = lane & 15;
    const int hi   = lane >> 4;
    const int wr   = wave >> 1, wc = wave & 1;

    // XCD swizzle: xcd owns 8 row-panels x 8 colb; per-XCD reuse set =
    // 8 c-panels (4 MiB as bf16=2) + Wt (2 MiB) ~ L2-resident.
    const int bid = blockIdx.x;
    const int xcd = bid & 7;
    const int q   = bid >> 3;            // 0..63
    const int rb  = (xcd * 8 + (q >> 3)) * 128;
    const int cb  = (q & 7) * 128;

    // per-lane fragment base addresses (A-frag mi rows rb+wr*64+mi*16+lr,
    // B-frag ni rows cb+wc*64+ni*16+lr; k-slice hi*8)
    unsigned long long ba[4], bb[4];
#pragma unroll
    for (int i = 0; i < 4; ++i) {
        ba[i] = (unsigned long long)(uintptr_t)
                (Cm + (size_t)(rb + wr * 64 + i * 16 + lr) * E_DIM + hi * 8);
        bb[i] = (unsigned long long)(uintptr_t)
                (Wt + (size_t)(cb + wc * 64 + i * 16 + lr) * E_DIM + hi * 8);
    }

    bf16x8 A[3][4], B[3][4];
    f32x4 acc[4][4] = {};

    // prologue: tiles 0 and 1 in flight (16 outstanding)
#pragma unroll
    for (int i = 0; i < 4; ++i) { LOAD16(A[0][i], ba[i], 0);  LOAD16(B[0][i], bb[i], 0);  }
#pragma unroll
    for (int i = 0; i < 4; ++i) { LOAD16(A[1][i], ba[i], 64); LOAD16(B[1][i], bb[i], 64); }

#pragma unroll
    for (int t = 0; t < NSTEPS; ++t) {
        const int su = t % 3;            // static under full unroll
        if (t + 2 < NSTEPS) {
            const int si = (t + 2) % 3;
            const int ko = (t + 2) * 64; // bytes (BK=32 bf16)
#pragma unroll
            for (int i = 0; i < 4; ++i) { LOAD16(A[si][i], ba[i], ko); LOAD16(B[si][i], bb[i], ko); }
        }
        // certify tile t (FIFO: newest 16 = tiles t+1, t+2)
        if (t + 2 < NSTEPS)      VMW(16);
        else if (t + 1 < NSTEPS) VMW(8);
        else                     VMW(0);

        __builtin_amdgcn_s_setprio(1);
#pragma unroll
        for (int mi = 0; mi < 4; ++mi)
#pragma unroll
            for (int ni = 0; ni < 4; ++ni)
                acc[mi][ni] = __builtin_amdgcn_mfma_f32_16x16x32_bf16(
                    A[su][mi], B[su][ni], acc[mi][ni], 0, 0, 0);
        __builtin_amdgcn_s_setprio(0);
    }

    // epilogue: delta[r] += sum_col u[r][col] * (Ais - Aem)[r][col]
    // C/D layout (16x16x32): col = lane&15, row = (lane>>4)*4 + reg
    const int colbase = cb + wc * 64 + lr;
    const int rowbase = rb + wr * 64 + hi * 4;
#pragma unroll
    for (int mi = 0; mi < 4; ++mi) {
#pragma unroll
        for (int jj = 0; jj < 4; ++jj) {
            const int r = rowbase + mi * 16 + jj;
            float v = 0.f;
#pragma unroll
            for (int ni = 0; ni < 4; ++ni) {
                const size_t idx = (size_t)r * E_DIM + colbase + ni * 16;
                v += acc[mi][ni][jj] * (Ais[idx] - Aem[idx]);
            }
            v += __shfl_xor(v, 1);
            v += __shfl_xor(v, 2);
            v += __shfl_xor(v, 4);
            v += __shfl_xor(v, 8);
            if (lr == 0) atomicAdd(&delta[r], v);
        }
    }
}

__global__ void hinge_sum(const float* __restrict__ delta, float* __restrict__ out) {
    float s = 0.f;
    for (int i = threadIdx.x; i < B_ROWS; i += 256)
        s += fmaxf(MARGIN + delta[i], 0.f);
#pragma unroll
    for (int off = 32; off > 0; off >>= 1) s += __shfl_down(s, off);
    __shared__ float wsum[4];
    int lane = threadIdx.x & 63, w = threadIdx.x >> 6;
    if (lane == 0) wsum[w] = s;
    __syncthreads();
    if (threadIdx.x == 0) out[0] = wsum[0] + wsum[1] + wsum[2] + wsum[3];
}

extern "C" void kernel_launch(void* const* d_in, const int* in_sizes, int n_in,
                              void* d_out, int out_size, void* d_ws, size_t ws_size,
                              hipStream_t stream) {
    const float* A_is = (const float*)d_in[0];
    const float* A_em = (const float*)d_in[1];
    const float* m    = (const float*)d_in[2];
    const float* tr_m = (const float*)d_in[3];
    const float* W    = (const float*)d_in[4];
    // d_in[5] = b : cancels in diag_is - diag_em, unused.
    float* out = (float*)d_out;

    char* ws = (char*)d_ws;
    __bf16* c     = (__bf16*)ws;                              // 16 MiB
    __bf16* wt    = (__bf16*)(ws + (size_t)16 * 1024 * 1024); //  2 MiB
    float*  delta = (float*) (ws + (size_t)18 * 1024 * 1024); // 32 KiB

    prep_combo<<<5152, 256, 0, stream>>>(m, tr_m, c, W, wt, delta);
    gemm_dot<<<512, 256, 0, stream>>>(c, wt, A_is, A_em, delta);
    hinge_sum<<<1, 256, 0, stream>>>(delta, out);
}

// Round 14
// 64.520 us; speedup vs baseline: 1.4843x; 1.4591x over previous
//
#include <hip/hip_runtime.h>
#include <hip/hip_bf16.h>

#define B_ROWS 8192
#define E_DIM  1024
#define MARGIN 0.2f
#define NSTEPS 32            // K-steps of BK=32

typedef __bf16 bf16x8 __attribute__((ext_vector_type(8)));
typedef float  f32x4  __attribute__((ext_vector_type(4)));

__device__ __forceinline__ void gload_lds16(const void* g, void* l) {
    __builtin_amdgcn_global_load_lds(
        (__attribute__((address_space(1))) void*)(g),
        (__attribute__((address_space(3))) void*)(l),
        16, 0, 0);
}

#define VMW8()  do { asm volatile("s_waitcnt vmcnt(8)" ::: "memory"); \
                     __builtin_amdgcn_sched_barrier(0); } while (0)
#define VMW0()  do { asm volatile("s_waitcnt vmcnt(0)" ::: "memory"); \
                     __builtin_amdgcn_sched_barrier(0); } while (0)
#define LGKM0() do { asm volatile("s_waitcnt lgkmcnt(0)" ::: "memory"); \
                     __builtin_amdgcn_sched_barrier(0); } while (0)

// blocks [0,4096): c = 0.4*m + 0.6*tr_m (bf16);
// blocks [4096,5120): Wt[n][e] = bf16(W[e][n]); blocks [5120,5152): zero delta.
__global__ __launch_bounds__(256)
void prep_combo(const float* __restrict__ m, const float* __restrict__ trm,
                __bf16* __restrict__ c,
                const float* __restrict__ W, __bf16* __restrict__ Wt,
                float* __restrict__ delta) {
    if (blockIdx.x < 4096) {
        size_t i = ((size_t)blockIdx.x * blockDim.x + threadIdx.x) * 8;
        float4 m0 = *(const float4*)(m + i);
        float4 m1 = *(const float4*)(m + i + 4);
        float4 t0 = *(const float4*)(trm + i);
        float4 t1 = *(const float4*)(trm + i + 4);
        bf16x8 v;
        v[0] = (__bf16)(0.4f*m0.x + 0.6f*t0.x);
        v[1] = (__bf16)(0.4f*m0.y + 0.6f*t0.y);
        v[2] = (__bf16)(0.4f*m0.z + 0.6f*t0.z);
        v[3] = (__bf16)(0.4f*m0.w + 0.6f*t0.w);
        v[4] = (__bf16)(0.4f*m1.x + 0.6f*t1.x);
        v[5] = (__bf16)(0.4f*m1.y + 0.6f*t1.y);
        v[6] = (__bf16)(0.4f*m1.z + 0.6f*t1.z);
        v[7] = (__bf16)(0.4f*m1.w + 0.6f*t1.w);
        *(bf16x8*)(c + i) = v;
    } else if (blockIdx.x < 5120) {
        __shared__ float tile[32][33];
        const int tb = blockIdx.x - 4096;
        const int bx = (tb & 31) * 32;          // n base
        const int by = (tb >> 5) * 32;          // e base
        const int tx = threadIdx.x & 31;
        const int ty0 = threadIdx.x >> 5;       // 8 rows/thread
#pragma unroll
        for (int r = 0; r < 32; r += 8)
            tile[r + ty0][tx] = W[(size_t)(by + r + ty0) * E_DIM + bx + tx];
        __syncthreads();
#pragma unroll
        for (int r = 0; r < 32; r += 8)
            Wt[(size_t)(bx + r + ty0) * E_DIM + by + tx] = (__bf16)tile[tx][r + ty0];
    } else {
        delta[(blockIdx.x - 5120) * 256 + threadIdx.x] = 0.f;
    }
}

// Barrier-free GEMM: u = c @ Wt^T. Each of the 4 waves owns a 64x64 output
// tile AND a private 2-slot LDS ring (A 4KB + B 4KB per slot). Waves stage
// their own operands (gload_lds, 8 x 16B/iter), gate on their OWN counted
// vmcnt(8) (exact per-wave FIFO), and NEVER synchronize with other waves:
// zero s_barrier in the kernel, so stalls de-correlate and 2 waves/SIMD
// cover each other. Frag reads use an XOR swizzle ((row&3)<<4 within 64B
// rows) applied on the global source (rule #21), giving uniform bank use.
// Fused epilogue: rowwise dot with (Ais - Aem) -> atomicAdd into delta[].
__global__ __launch_bounds__(256)
void gemm_dot(const __bf16* __restrict__ Cm, const __bf16* __restrict__ Wt,
              const float* __restrict__ Ais, const float* __restrict__ Aem,
              float* __restrict__ delta) {
    __shared__ char lds[4][2][8192];   // [wave][slot][A:0-4095 | B:4096-8191]

    const int tid  = threadIdx.x;
    const int lane = tid & 63;
    const int wave = tid >> 6;
    const int lr   = lane & 15;
    const int hi   = lane >> 4;
    const int wr   = wave >> 1, wc = wave & 1;

    // XCD swizzle: xcd owns 8 row-panels x 8 colb; per-XCD reuse set =
    // 8 c-panels (2 MiB) + Wt (2 MiB) ~ L2-resident.
    const int bid = blockIdx.x;
    const int xcd = bid & 7;
    const int q   = bid >> 3;            // 0..63
    const int rb  = (xcd * 8 + (q >> 3)) * 128;
    const int cb  = (q & 7) * 128;

    // per-lane stage sources (4 A + 4 B), k0 = 0; advance +64 B per K-step.
    // load i covers LDS bytes [i*1024 + lane*16); row = 16 B-rows per issue.
    const char* srcA[4];
    const char* srcB[4];
    char*       dstA[4];
    char*       dstB[4];
#pragma unroll
    for (int i = 0; i < 4; ++i) {
        const int d   = i * 1024 + lane * 16;
        const int row = d >> 6;                       // 0..63
        const int sw  = (d & 63) ^ ((row & 3) << 4);  // inverse swizzle on source
        srcA[i] = (const char*)Cm + ((size_t)(rb + wr * 64 + row) * E_DIM) * 2 + sw;
        srcB[i] = (const char*)Wt + ((size_t)(cb + wc * 64 + row) * E_DIM) * 2 + sw;
        dstA[i] = &lds[wave][0][0]    + i * 1024 + lane * 16;
        dstB[i] = &lds[wave][0][4096] + i * 1024 + lane * 16;
    }

    f32x4 acc[4][4] = {};

    // prologue: stage tile 0 into slot 0 (8 loads outstanding)
#pragma unroll
    for (int i = 0; i < 4; ++i) {
        gload_lds16(srcA[i], dstA[i]);
        gload_lds16(srcB[i], dstB[i]);
    }

    for (int t = 0; t < NSTEPS; ++t) {
        const int s = t & 1;

        // stage tile t+1 into the other slot (issued before the wait: these
        // 8 stay in flight across this whole iteration)
        if (t + 1 < NSTEPS) {
            const int ko = (t + 1) * 64;              // bytes (BK=32 bf16)
            const int so = (s ^ 1) * 8192;
#pragma unroll
            for (int i = 0; i < 4; ++i) {
                gload_lds16(srcA[i] + ko, dstA[i] + so);
                gload_lds16(srcB[i] + ko, dstB[i] + so);
            }
            VMW8();      // per-wave FIFO: tile t's 8 loads have landed
        } else {
            VMW0();
        }

        // frag reads from own slot (swizzled; uniform bank distribution)
        const char* base = &lds[wave][0][0] + s * 8192;
        const int   xo   = (hi * 16) ^ ((lr & 3) << 4);
        bf16x8 a[4], b[4];
#pragma unroll
        for (int mi = 0; mi < 4; ++mi)
            a[mi] = *(const bf16x8*)(base + (mi * 16 + lr) * 64 + xo);
#pragma unroll
        for (int ni = 0; ni < 4; ++ni)
            b[ni] = *(const bf16x8*)(base + 4096 + (ni * 16 + lr) * 64 + xo);
        LGKM0();

        __builtin_amdgcn_s_setprio(1);
#pragma unroll
        for (int mi = 0; mi < 4; ++mi)
#pragma unroll
            for (int ni = 0; ni < 4; ++ni)
                acc[mi][ni] = __builtin_amdgcn_mfma_f32_16x16x32_bf16(
                    a[mi], b[ni], acc[mi][ni], 0, 0, 0);
        __builtin_amdgcn_s_setprio(0);
    }

    // epilogue: delta[r] += sum_col u[r][col] * (Ais - Aem)[r][col]
    // C/D layout (16x16x32): col = lane&15, row = (lane>>4)*4 + reg
    const int colbase = cb + wc * 64 + lr;
    const int rowbase = rb + wr * 64 + hi * 4;
#pragma unroll
    for (int mi = 0; mi < 4; ++mi) {
#pragma unroll
        for (int jj = 0; jj < 4; ++jj) {
            const int r = rowbase + mi * 16 + jj;
            float v = 0.f;
#pragma unroll
            for (int ni = 0; ni < 4; ++ni) {
                const size_t idx = (size_t)r * E_DIM + colbase + ni * 16;
                v += acc[mi][ni][jj] * (Ais[idx] - Aem[idx]);
            }
            v += __shfl_xor(v, 1);
            v += __shfl_xor(v, 2);
            v += __shfl_xor(v, 4);
            v += __shfl_xor(v, 8);
            if (lr == 0) atomicAdd(&delta[r], v);
        }
    }
}

__global__ void hinge_sum(const float* __restrict__ delta, float* __restrict__ out) {
    float s = 0.f;
    for (int i = threadIdx.x; i < B_ROWS; i += 256)
        s += fmaxf(MARGIN + delta[i], 0.f);
#pragma unroll
    for (int off = 32; off > 0; off >>= 1) s += __shfl_down(s, off);
    __shared__ float wsum[4];
    int lane = threadIdx.x & 63, w = threadIdx.x >> 6;
    if (lane == 0) wsum[w] = s;
    __syncthreads();
    if (threadIdx.x == 0) out[0] = wsum[0] + wsum[1] + wsum[2] + wsum[3];
}

extern "C" void kernel_launch(void* const* d_in, const int* in_sizes, int n_in,
                              void* d_out, int out_size, void* d_ws, size_t ws_size,
                              hipStream_t stream) {
    const float* A_is = (const float*)d_in[0];
    const float* A_em = (const float*)d_in[1];
    const float* m    = (const float*)d_in[2];
    const float* tr_m = (const float*)d_in[3];
    const float* W    = (const float*)d_in[4];
    // d_in[5] = b : cancels in diag_is - diag_em, unused.
    float* out = (float*)d_out;

    char* ws = (char*)d_ws;
    __bf16* c     = (__bf16*)ws;                              // 16 MiB
    __bf16* wt    = (__bf16*)(ws + (size_t)16 * 1024 * 1024); //  2 MiB
    float*  delta = (float*) (ws + (size_t)18 * 1024 * 1024); // 32 KiB

    prep_combo<<<5152, 256, 0, stream>>>(m, tr_m, c, W, wt, delta);
    gemm_dot<<<512, 256, 0, stream>>>(c, wt, A_is, A_em, delta);
    hinge_sum<<<1, 256, 0, stream>>>(delta, out);
}

// Round 15
// 49.556 us; speedup vs baseline: 1.9325x; 1.3020x over previous
//
#include <hip/hip_runtime.h>
#include <hip/hip_bf16.h>
#include <hip/hip_fp8.h>

#define B_ROWS 8192
#define E_DIM  1024
#define MARGIN 0.2f
#define BK 64                 // fp8 elements per K-step
#define NSTEPS (E_DIM / BK)   // 16
#define WSCALE 16.0f          // W scaled into e4m3 sweet spot; undone in epilogue

typedef float f32x4 __attribute__((ext_vector_type(4)));

__device__ __forceinline__ void gload_lds16(const void* g, void* l) {
    __builtin_amdgcn_global_load_lds(
        (__attribute__((address_space(1))) void*)(g),
        (__attribute__((address_space(3))) void*)(l),
        16, 0, 0);
}

#define GATE4() do { asm volatile("s_waitcnt vmcnt(4)" ::: "memory"); \
                     __builtin_amdgcn_sched_barrier(0); } while (0)
#define GATE0() do { asm volatile("s_waitcnt vmcnt(0)" ::: "memory"); \
                     __builtin_amdgcn_sched_barrier(0); } while (0)
#define RBAR()  do { __builtin_amdgcn_s_barrier(); \
                     __builtin_amdgcn_sched_barrier(0); } while (0)
#define LGKM0() do { asm volatile("s_waitcnt lgkmcnt(0)" ::: "memory"); \
                     __builtin_amdgcn_sched_barrier(0); } while (0)

__device__ __forceinline__ unsigned char to_fp8(float x) {
    return __hip_fp8_e4m3(x).__x;
}

// blocks [0,4096): c8 = fp8(0.4*m + 0.6*tr_m);
// blocks [4096,5120): Wt8[n][e] = fp8(16 * W[e][n]); blocks [5120,5152): zero delta.
__global__ __launch_bounds__(256)
void prep_combo(const float* __restrict__ m, const float* __restrict__ trm,
                unsigned char* __restrict__ c8,
                const float* __restrict__ W, unsigned char* __restrict__ Wt8,
                float* __restrict__ delta) {
    if (blockIdx.x < 4096) {
        size_t i = ((size_t)blockIdx.x * blockDim.x + threadIdx.x) * 8;
        float4 m0 = *(const float4*)(m + i);
        float4 m1 = *(const float4*)(m + i + 4);
        float4 t0 = *(const float4*)(trm + i);
        float4 t1 = *(const float4*)(trm + i + 4);
        union { unsigned char b[8]; unsigned long long u; } r;
        r.b[0] = to_fp8(0.4f*m0.x + 0.6f*t0.x);
        r.b[1] = to_fp8(0.4f*m0.y + 0.6f*t0.y);
        r.b[2] = to_fp8(0.4f*m0.z + 0.6f*t0.z);
        r.b[3] = to_fp8(0.4f*m0.w + 0.6f*t0.w);
        r.b[4] = to_fp8(0.4f*m1.x + 0.6f*t1.x);
        r.b[5] = to_fp8(0.4f*m1.y + 0.6f*t1.y);
        r.b[6] = to_fp8(0.4f*m1.z + 0.6f*t1.z);
        r.b[7] = to_fp8(0.4f*m1.w + 0.6f*t1.w);
        *(unsigned long long*)(c8 + i) = r.u;
    } else if (blockIdx.x < 5120) {
        __shared__ float tile[32][33];
        const int tb = blockIdx.x - 4096;
        const int bx = (tb & 31) * 32;          // n base
        const int by = (tb >> 5) * 32;          // e base
        const int tx = threadIdx.x & 31;
        const int ty0 = threadIdx.x >> 5;       // 8 rows/thread
#pragma unroll
        for (int r = 0; r < 32; r += 8)
            tile[r + ty0][tx] = W[(size_t)(by + r + ty0) * E_DIM + bx + tx];
        __syncthreads();
#pragma unroll
        for (int r = 0; r < 32; r += 8)
            Wt8[(size_t)(bx + r + ty0) * E_DIM + by + tx] =
                to_fp8(tile[tx][r + ty0] * WSCALE);
    } else {
        delta[(blockIdx.x - 5120) * 256 + threadIdx.x] = 0.f;
    }
}

// fp8 port of the R8 skeleton (best known): ring-of-3 LDS staging, counted
// per-thread vmcnt gates (4 loads/thread/tile, GATE4 certifies tile t), one
// raw barrier per K-step. BK=64 fp8 in the same 8 KiB tiles -> NSTEPS=16:
// HALF the LDS write bytes, HALF the LDS read bytes (b64 frags), HALF the
// gload_lds per K vs bf16. Swizzle (row&7)<<3 on 8B granules applied on the
// global source AND the ds_read (rule #21); staging stays 64B-coalesced.
// mfma_f32_16x16x32_fp8_fp8 (A/B: lane row=l&15, k=(l>>4)*8..+7, 8B/lane).
// Epilogue: rowwise dot with (Ais - Aem), /WSCALE, atomicAdd into delta[].
__global__ __launch_bounds__(256)
void gemm_dot(const unsigned char* __restrict__ Cm, const unsigned char* __restrict__ Wt,
              const float* __restrict__ Ais, const float* __restrict__ Aem,
              float* __restrict__ delta) {
    __shared__ char smem[49152];   // A slots at slot*8192, B at 24576+slot*8192

    const int tid  = threadIdx.x;
    const int lane = tid & 63;
    const int wave = tid >> 6;
    const int lr   = lane & 15;
    const int hi   = lane >> 4;
    const int wr   = wave >> 1, wc = wave & 1;

    // XCD swizzle: xcd owns 8 row-panels x 8 colb; per-XCD reuse set =
    // 8 c8-panels (1 MiB) + Wt8 (1 MiB) ~ L2-resident.
    const int bid = blockIdx.x;
    const int xcd = bid & 7;
    const int q   = bid >> 3;            // 0..63
    const int rb  = (xcd * 8 + (q >> 3)) * 128;
    const int cb  = (q & 7) * 128;

    auto stage = [&](int slot, int k0) {
#pragma unroll
        for (int i = 0; i < 2; ++i) {
            const int off = i * 4096 + tid * 16;
            const int row = off >> 6;                      // 64 B per 64-fp8 row
            const int kb  = (off & 63) ^ ((row & 7) << 3); // inverse swizzle on src
            gload_lds16(Cm + (size_t)(rb + row) * E_DIM + k0 + kb,
                        smem + slot * 8192 + off);
            gload_lds16(Wt + (size_t)(cb + row) * E_DIM + k0 + kb,
                        smem + 24576 + slot * 8192 + off);
        }
    };

    f32x4 acc[4][4] = {};

    stage(0, 0);
    stage(1, BK);

    int s0 = 0, s1 = 1, s2 = 2;
    for (int t = 0; t < NSTEPS; ++t) {
        if (t + 1 < NSTEPS) GATE4(); else GATE0();
        RBAR();

        // frag reads: 8B each, 2 k-subtiles (k=0..31, 32..63) per row
        const char* Ab = smem + s0 * 8192;
        const char* Bb = smem + 24576 + s0 * 8192;
        const int swz = (lr & 7) << 3;       // row&7 == lr&7 (bases are x8)
        const int o0  = (hi * 8) ^ swz;
        const int o1  = (32 + hi * 8) ^ swz;
        long a0[4], a1[4], b0[4], b1[4];
#pragma unroll
        for (int mi = 0; mi < 4; ++mi) {
            const int ro = (wr * 64 + mi * 16 + lr) * 64;
            a0[mi] = *(const long*)(Ab + ro + o0);
            a1[mi] = *(const long*)(Ab + ro + o1);
        }
#pragma unroll
        for (int ni = 0; ni < 4; ++ni) {
            const int ro = (wc * 64 + ni * 16 + lr) * 64;
            b0[ni] = *(const long*)(Bb + ro + o0);
            b1[ni] = *(const long*)(Bb + ro + o1);
        }
        LGKM0();

        if (t + 2 < NSTEPS) stage(s2, (t + 2) * BK);

        __builtin_amdgcn_s_setprio(1);
#pragma unroll
        for (int mi = 0; mi < 4; ++mi)
#pragma unroll
            for (int ni = 0; ni < 4; ++ni) {
                acc[mi][ni] = __builtin_amdgcn_mfma_f32_16x16x32_fp8_fp8(
                    a0[mi], b0[ni], acc[mi][ni], 0, 0, 0);
                acc[mi][ni] = __builtin_amdgcn_mfma_f32_16x16x32_fp8_fp8(
                    a1[mi], b1[ni], acc[mi][ni], 0, 0, 0);
            }
        __builtin_amdgcn_s_setprio(0);

        int tmp = s0; s0 = s1; s1 = s2; s2 = tmp;
    }

    // epilogue: delta[r] += (1/WSCALE) * sum_col u[r][col] * (Ais - Aem)[r][col]
    // C/D layout (16x16x32, dtype-independent): col = lane&15, row = (lane>>4)*4 + reg
    const int colbase = cb + wc * 64 + lr;
    const int rowbase = rb + wr * 64 + hi * 4;
#pragma unroll
    for (int mi = 0; mi < 4; ++mi) {
#pragma unroll
        for (int jj = 0; jj < 4; ++jj) {
            const int r = rowbase + mi * 16 + jj;
            float v = 0.f;
#pragma unroll
            for (int ni = 0; ni < 4; ++ni) {
                const size_t idx = (size_t)r * E_DIM + colbase + ni * 16;
                v += acc[mi][ni][jj] * (Ais[idx] - Aem[idx]);
            }
            v += __shfl_xor(v, 1);
            v += __shfl_xor(v, 2);
            v += __shfl_xor(v, 4);
            v += __shfl_xor(v, 8);
            if (lr == 0) atomicAdd(&delta[r], v * (1.0f / WSCALE));
        }
    }
}

__global__ void hinge_sum(const float* __restrict__ delta, float* __restrict__ out) {
    float s = 0.f;
    for (int i = threadIdx.x; i < B_ROWS; i += 256)
        s += fmaxf(MARGIN + delta[i], 0.f);
#pragma unroll
    for (int off = 32; off > 0; off >>= 1) s += __shfl_down(s, off);
    __shared__ float wsum[4];
    int lane = threadIdx.x & 63, w = threadIdx.x >> 6;
    if (lane == 0) wsum[w] = s;
    __syncthreads();
    if (threadIdx.x == 0) out[0] = wsum[0] + wsum[1] + wsum[2] + wsum[3];
}

extern "C" void kernel_launch(void* const* d_in, const int* in_sizes, int n_in,
                              void* d_out, int out_size, void* d_ws, size_t ws_size,
                              hipStream_t stream) {
    const float* A_is = (const float*)d_in[0];
    const float* A_em = (const float*)d_in[1];
    const float* m    = (const float*)d_in[2];
    const float* tr_m = (const float*)d_in[3];
    const float* W    = (const float*)d_in[4];
    // d_in[5] = b : cancels in diag_is - diag_em, unused.
    float* out = (float*)d_out;

    char* ws = (char*)d_ws;
    unsigned char* c8  = (unsigned char*)ws;                             // 8 MiB
    unsigned char* wt8 = (unsigned char*)(ws + (size_t)8 * 1024 * 1024); // 1 MiB
    float*         delta = (float*)(ws + (size_t)9 * 1024 * 1024);       // 32 KiB

    prep_combo<<<5152, 256, 0, stream>>>(m, tr_m, c8, W, wt8, delta);
    gemm_dot<<<512, 256, 0, stream>>>(c8, wt8, A_is, A_em, delta);
    hinge_sum<<<1, 256, 0, stream>>>(delta, out);
}